// Round 17
// baseline (37.887 us; speedup 1.0000x reference)
//
#include <hip/hip_runtime.h>

#define SEQ 2048
#define DIM 6
#define VROW 2056            // padded LDS V^T row stride (elements)

typedef _Float16 half4F __attribute__((ext_vector_type(4)));
typedef short bf16x4 __attribute__((ext_vector_type(4)));
typedef float f32x4 __attribute__((ext_vector_type(4)));

union FragU { uint2 u; half4F h; bf16x4 b; };

__device__ __forceinline__ unsigned pkh(float a, float b) {
    return __builtin_bit_cast(unsigned, __builtin_amdgcn_cvt_pkrtz(a, b));
}
// bf16 round-to-nearest-even via integer rounding (staging only; finite inputs).
__device__ __forceinline__ unsigned bf16rn(float x) {
    unsigned u = __builtin_bit_cast(unsigned, x);
    return (u + 0x7FFFu + ((u >> 16) & 1u)) >> 16;
}
// Packed truncating f32->bf16 pair: ONE v_perm_b32 (hi16(b)<<16 | hi16(a)).
__device__ __forceinline__ unsigned pkbf_trunc(float a, float b) {
    return __builtin_amdgcn_perm(__builtin_bit_cast(unsigned, b),
                                 __builtin_bit_cast(unsigned, a),
                                 0x07060302u);
}

__device__ __forceinline__ f32x4 mfma_bf16_(bf16x4 a, bf16x4 b, f32x4 c) {
#if __has_builtin(__builtin_amdgcn_mfma_f32_16x16x16bf16_1k)
    return __builtin_amdgcn_mfma_f32_16x16x16bf16_1k(a, b, c, 0, 0, 0);
#else
    f32x4 d;
    asm("v_mfma_f32_16x16x16_bf16 %0, %1, %2, %3"
        : "=v"(d) : "v"(a), "v"(b), "v"(c));
    return d;
#endif
}

// ws layout:
//   Kc   [B][SEQ][8] fp16 : compacted K' = {k*log2e x6, bias(0 real/-1024 pad), 0}
//   VcT  [B][7][SEQ] bf16 : compacted V^T rows 0..5, row6 = ones; pads zeroed
//   rowl [B][SEQ] int     : compacted index list (rows == cols, same mask)
//   nuArr[B] int          : number of unmasked positions
// Masked cols excluded (exact: their reference softmax weight underflows to 0).
// Masked rows = mean(V over ALL t), written directly by prep.

__launch_bounds__(256)
__global__ void prep(const float* __restrict__ X, const int* __restrict__ mask,
                     const float* __restrict__ Wk, const float* __restrict__ bk,
                     const float* __restrict__ Wv, const float* __restrict__ bv,
                     __fp16* __restrict__ Kc, unsigned short* __restrict__ VcT,
                     int* __restrict__ rowl, int* __restrict__ nuArr,
                     float* __restrict__ out) {
    __shared__ int sA[256], sB[256];
    __shared__ float vsr[6][256];
    const int b = blockIdx.x, tid = threadIdx.x;
    const float* Xb = X + (size_t)b * SEQ * DIM;
    const int* mb = mask + (size_t)b * SEQ;
    const float L2E = 1.44269504088896f;

    // local mask counts over this thread's contiguous 8-row segment
    const int t0 = tid * 8;
    int mloc[8]; int c = 0;
#pragma unroll
    for (int j = 0; j < 8; ++j) { mloc[j] = (mb[t0 + j] != 0); c += mloc[j]; }
    sA[tid] = c;
    __syncthreads();
    // Hillis-Steele inclusive scan over 256 per-thread counts
    int* src = sA; int* dst = sB;
    for (int off = 1; off < 256; off <<= 1) {
        int v = src[tid];
        if (tid >= off) v += src[tid - off];
        dst[tid] = v;
        __syncthreads();
        int* tmp = src; src = dst; dst = tmp;
    }
    const int Nu = src[255];
    int slot = src[tid] - c;  // exclusive base for this segment
    if (tid == 0) nuArr[b] = Nu;

    float vsum[6] = {0, 0, 0, 0, 0, 0};
#pragma unroll
    for (int j = 0; j < 8; ++j) {
        const int t = t0 + j;
        const float2* xp = reinterpret_cast<const float2*>(Xb + t * DIM);
        float2 x01 = xp[0], x23 = xp[1], x45 = xp[2];
        float x[DIM] = {x01.x, x01.y, x23.x, x23.y, x45.x, x45.y};
        float kk[DIM], vv[DIM];
#pragma unroll
        for (int r = 0; r < DIM; ++r) {
            float k = bk[r], v = bv[r];
#pragma unroll
            for (int cc = 0; cc < DIM; ++cc) {
                k = fmaf(Wk[r * DIM + cc], x[cc], k);
                v = fmaf(Wv[r * DIM + cc], x[cc], v);
            }
            kk[r] = k * L2E;
            vv[r] = v;
            vsum[r] += v;
        }
        if (mloc[j]) {
            uint4 kw;
            kw.x = pkh(kk[0], kk[1]);
            kw.y = pkh(kk[2], kk[3]);
            kw.z = pkh(kk[4], kk[5]);
            kw.w = pkh(0.0f, 0.0f);  // bias 0 (all compacted cols unmasked)
            *reinterpret_cast<uint4*>(Kc + ((size_t)b * SEQ + slot) * 8) = kw;
            unsigned short* vb = VcT + (size_t)b * 7 * SEQ + slot;
#pragma unroll
            for (int r = 0; r < DIM; ++r) vb[r * SEQ] = (unsigned short)bf16rn(vv[r]);
            vb[6 * SEQ] = 0x3F80u;  // ones row (denominator)
            rowl[(size_t)b * SEQ + slot] = t;
            ++slot;
        }
    }
    // pad columns to a multiple of 16 (pads: bias=-1024 -> p==0; V zeroed)
    const int NT16 = (Nu + 15) & ~15;
    if (tid < NT16 - Nu) {
        const int s = Nu + tid;
        uint4 kw; kw.x = 0; kw.y = 0; kw.z = 0; kw.w = pkh(-1024.0f, 0.0f);
        *reinterpret_cast<uint4*>(Kc + ((size_t)b * SEQ + s) * 8) = kw;
        unsigned short* vb = VcT + (size_t)b * 7 * SEQ + s;
#pragma unroll
        for (int r = 0; r < 7; ++r) vb[r * SEQ] = 0;
    }
    // mean of V over ALL t (tree reduce, deterministic)
#pragma unroll
    for (int r = 0; r < DIM; ++r) vsr[r][tid] = vsum[r];
    __syncthreads();
    for (int off = 128; off > 0; off >>= 1) {
        if (tid < off) {
#pragma unroll
            for (int r = 0; r < DIM; ++r) vsr[r][tid] += vsr[r][tid + off];
        }
        __syncthreads();
    }
    float meanV[DIM];
#pragma unroll
    for (int r = 0; r < DIM; ++r) meanV[r] = vsr[r][0] * (1.0f / SEQ);
    // masked rows: uniform softmax over all t -> meanV (f32-exact)
#pragma unroll
    for (int j = 0; j < 8; ++j) {
        if (!mloc[j]) {
            float* o = out + ((size_t)b * SEQ + t0 + j) * DIM;
            o[0] = meanV[0]; o[1] = meanV[1]; o[2] = meanV[2];
            o[3] = meanV[3]; o[4] = meanV[4]; o[5] = meanV[5];
        }
    }
}

// 4 waves/block, one 16-row compacted s-tile per wave (64 rows/block).
__launch_bounds__(256, 2)
__global__ void attn_mfma(const float* __restrict__ X,
                          const float* __restrict__ Wq, const float* __restrict__ bq,
                          const __fp16* __restrict__ Kc,
                          const unsigned short* __restrict__ VcT,
                          const int* __restrict__ rowl, const int* __restrict__ nuArr,
                          float* __restrict__ out) {
    __shared__ __align__(16) __fp16 Ksm[SEQ * 8];           // 32 KB
    __shared__ __align__(16) unsigned short Vt[7 * VROW];   // 28.8 KB

    const int b = blockIdx.x >> 5, sc = blockIdx.x & 31;
    const int tid = threadIdx.x;
    const int Nu = nuArr[b];
    const int s_base = sc * 64;
    if (s_base >= Nu) return;  // whole block idle (typical: half the grid)
    const int NT16 = (Nu + 15) & ~15;

    // bulk-stage compacted K'/V^T from L2
    const uint4* ks = reinterpret_cast<const uint4*>(Kc + (size_t)b * SEQ * 8);
    for (int i = tid; i < NT16; i += 256)
        reinterpret_cast<uint4*>(Ksm)[i] = ks[i];
    const int nch = NT16 >> 3;
    for (int i = tid; i < 7 * nch; i += 256) {
        const int r = i / nch, cc = i - r * nch;
        *reinterpret_cast<uint4*>(&Vt[r * VROW + cc * 8]) =
            *reinterpret_cast<const uint4*>(&VcT[((size_t)b * 7 + r) * SEQ + cc * 8]);
    }
    __syncthreads();

    const int lane = tid & 63, wid = tid >> 6;
    const int s0 = s_base + wid * 16;
    if (s0 >= Nu) return;  // after barrier: safe
    const int r15 = lane & 15, g = lane >> 4;
    const int sidx = s0 + r15;
    const int srow = rowl[(size_t)b * SEQ + (sidx < Nu ? sidx : Nu - 1)];

    // Q' projection for compacted row srow (4 lane-copies per row)
    const float* Xb = X + (size_t)b * SEQ * DIM;
    float qq[DIM];
    {
        const float2* xp = reinterpret_cast<const float2*>(Xb + srow * DIM);
        float2 x01 = xp[0], x23 = xp[1], x45 = xp[2];
        float x[DIM] = {x01.x, x01.y, x23.x, x23.y, x45.x, x45.y};
#pragma unroll
        for (int r = 0; r < DIM; ++r) {
            float q = bq[r];
#pragma unroll
            for (int cc = 0; cc < DIM; ++cc) q = fmaf(Wq[r * DIM + cc], x[cc], q);
            qq[r] = q;
        }
    }
    FragU qf;
    qf.u.x = (g == 0) ? pkh(qq[0], qq[1]) : (g == 1) ? pkh(qq[4], qq[5]) : 0u;
    qf.u.y = (g == 0) ? pkh(qq[2], qq[3]) : (g == 1) ? pkh(1.0f, 0.0f) : 0u;

    const f32x4 zero4 = {0.0f, 0.0f, 0.0f, 0.0f};
    f32x4 acc = zero4;
    const int ntiles = NT16 >> 4;
    {
        const int dcl = (r15 < 6) ? r15 : 6;
        int kidx = r15 * 8 + (g & 1) * 4;
        int vidx = dcl * VROW + g * 4;
#pragma unroll 2
        for (int tt = 0; tt < ntiles; ++tt) {
            half4F kf = *reinterpret_cast<const half4F*>(&Ksm[kidx]);
            bf16x4 vf = *reinterpret_cast<const bf16x4*>(&Vt[vidx]);
            f32x4 d = __builtin_amdgcn_mfma_f32_16x16x16f16(kf, qf.h, zero4, 0, 0, 0);
            FragU pa;
            pa.u.x = pkbf_trunc(__builtin_amdgcn_exp2f(d[0]),
                                __builtin_amdgcn_exp2f(d[1]));
            pa.u.y = pkbf_trunc(__builtin_amdgcn_exp2f(d[2]),
                                __builtin_amdgcn_exp2f(d[3]));
            acc = mfma_bf16_(pa.b, vf, acc);
            kidx += 128;
            vidx += 16;
        }
    }

    // Epilogue: scatter cols 0..5 / denominator col 6
    const int srcl = (lane & 48) | 6;
#pragma unroll
    for (int r = 0; r < 4; ++r) {
        const float dnm = __shfl(acc[r], srcl);
        const float val = acc[r] * __builtin_amdgcn_rcpf(dnm);
        const int oidx = s0 + g * 4 + r;
        if (r15 < 6 && oidx < Nu) {
            const int orow = rowl[(size_t)b * SEQ + oidx];
            out[((size_t)b * SEQ + orow) * DIM + r15] = val;
        }
    }
}

extern "C" void kernel_launch(void* const* d_in, const int* in_sizes, int n_in,
                              void* d_out, int out_size, void* d_ws, size_t ws_size,
                              hipStream_t stream) {
    const float* X  = (const float*)d_in[0];
    const int* mask = (const int*)d_in[1];
    const float* Wq = (const float*)d_in[2];
    const float* bq = (const float*)d_in[3];
    const float* Wk = (const float*)d_in[4];
    const float* bk = (const float*)d_in[5];
    const float* Wv = (const float*)d_in[6];
    const float* bv = (const float*)d_in[7];
    float* out = (float*)d_out;

    const int B = in_sizes[0] / (SEQ * DIM);

    __fp16* Kc = (__fp16*)d_ws;                                       // B*SEQ*8
    unsigned short* VcT = (unsigned short*)(Kc + (size_t)B * SEQ * 8);  // B*7*SEQ
    int* rowl = (int*)(VcT + (size_t)B * 7 * SEQ);                    // B*SEQ
    int* nuArr = rowl + (size_t)B * SEQ;                              // B

    prep<<<dim3(B), 256, 0, stream>>>(X, mask, Wk, bk, Wv, bv,
                                      Kc, VcT, rowl, nuArr, out);
    attn_mfma<<<dim3(B * 32), 256, 0, stream>>>(X, Wq, bq, Kc, VcT, rowl, nuArr, out);
}

// Round 18
// 24.758 us; speedup vs baseline: 1.5303x; 1.5303x over previous
//
#include <hip/hip_runtime.h>

#define SEQ 2048
#define DIM 6
#define NW 8
#define BLOCK (NW * 64)      // 512 threads
#define VROW 2056            // padded V^T row stride (elements)

typedef _Float16 half4F __attribute__((ext_vector_type(4)));
typedef short bf16x4 __attribute__((ext_vector_type(4)));
typedef float f32x4 __attribute__((ext_vector_type(4)));

union FragU { uint2 u; half4F h; bf16x4 b; };

__device__ __forceinline__ unsigned pkh(float a, float b) {
    return __builtin_bit_cast(unsigned, __builtin_amdgcn_cvt_pkrtz(a, b));
}
// bf16 round-to-nearest-even via integer rounding (staging only; finite inputs).
__device__ __forceinline__ unsigned bf16rn(float x) {
    unsigned u = __builtin_bit_cast(unsigned, x);
    return (u + 0x7FFFu + ((u >> 16) & 1u)) >> 16;
}
// Packed truncating f32->bf16 pair: ONE v_perm_b32 (hi16(b)<<16 | hi16(a)).
__device__ __forceinline__ unsigned pkbf_trunc(float a, float b) {
    return __builtin_amdgcn_perm(__builtin_bit_cast(unsigned, b),
                                 __builtin_bit_cast(unsigned, a),
                                 0x07060302u);
}

__device__ __forceinline__ f32x4 mfma_bf16_(bf16x4 a, bf16x4 b, f32x4 c) {
#if __has_builtin(__builtin_amdgcn_mfma_f32_16x16x16bf16_1k)
    return __builtin_amdgcn_mfma_f32_16x16x16bf16_1k(a, b, c, 0, 0, 0);
#else
    f32x4 d;
    asm("v_mfma_f32_16x16x16_bf16 %0, %1, %2, %3"
        : "=v"(d) : "v"(a), "v"(b), "v"(c));
    return d;
#endif
}

// Single fused kernel. Per block (16 per batch):
//   1) per-batch mask prefix-scan in LDS (redundant per block, deterministic)
//   2) project all t; stage COMPACTED K' (fp16) / V^T (bf16) + rowlist in LDS
//      (masked cols excluded -- exact: their softmax weight underflows to 0)
//   3) block 0 writes masked rows' outputs = mean(V over ALL t) (f32 reduce)
//   4) r15 MFMA loop over NT16 compacted cols for this block's compacted rows
// LDS: Ksm 32K | Vt 28.8K | rowl 4K | wred 256B = 65.9 KB (dynamic, opt-in).

__launch_bounds__(BLOCK, 4)
__global__ void attn_fused(const float* __restrict__ X,
                           const int* __restrict__ mask,
                           const float* __restrict__ Wq, const float* __restrict__ bq,
                           const float* __restrict__ Wk, const float* __restrict__ bk,
                           const float* __restrict__ Wv, const float* __restrict__ bv,
                           float* __restrict__ out) {
    extern __shared__ __align__(16) char smem[];
    __fp16* Ksm = (__fp16*)smem;                                   // [2048][8]
    unsigned short* Vt = (unsigned short*)(smem + 32768);          // [7][VROW]
    unsigned short* rowl = (unsigned short*)(smem + 32768 + 7 * VROW * 2);
    float* wred = (float*)(smem + 32768 + 7 * VROW * 2 + 4096);    // [8][8]
    int* scanA = (int*)smem;          // aliases Ksm; dead before K writes
    int* scanB = (int*)(smem + 2048);

    const int blk = blockIdx.x & 15;
    const int b = blockIdx.x >> 4;
    const int tid = threadIdx.x;
    const int lane = tid & 63, wid = tid >> 6;
    const float* Xb = X + (size_t)b * SEQ * DIM;
    const int* mb = mask + (size_t)b * SEQ;
    const float L2E = 1.44269504088896f;

    // ---- Phase 1: mask counts + block-wide prefix scan (512 entries) ----
    const int t0 = tid * 4;
    int mloc[4]; int c = 0;
#pragma unroll
    for (int j = 0; j < 4; ++j) { mloc[j] = (mb[t0 + j] != 0); c += mloc[j]; }
    scanA[tid] = c;
    __syncthreads();
    int* src = scanA; int* dst = scanB;
    for (int off = 1; off < BLOCK; off <<= 1) {
        int v = src[tid];
        if (tid >= off) v += src[tid - off];
        dst[tid] = v;
        __syncthreads();
        int* tmp = src; src = dst; dst = tmp;
    }
    const int Nu = src[BLOCK - 1];
    int slot = src[tid] - c;  // exclusive base
    __syncthreads();          // scan region free after this

    const int rowbase = blk * 128;
    if (rowbase >= Nu && blk != 0) return;  // idle block: only paid the scan

    // ---- Phase 2: project all t; compacted staging + V running sum ----
    float vsum[DIM] = {0, 0, 0, 0, 0, 0};
#pragma unroll
    for (int j = 0; j < 4; ++j) {
        const int t = t0 + j;
        const float2* xp = reinterpret_cast<const float2*>(Xb + t * DIM);
        float2 x01 = xp[0], x23 = xp[1], x45 = xp[2];
        float x[DIM] = {x01.x, x01.y, x23.x, x23.y, x45.x, x45.y};
        float kk[DIM], vv[DIM];
#pragma unroll
        for (int r = 0; r < DIM; ++r) {
            float k = bk[r], v = bv[r];
#pragma unroll
            for (int cc = 0; cc < DIM; ++cc) {
                k = fmaf(Wk[r * DIM + cc], x[cc], k);
                v = fmaf(Wv[r * DIM + cc], x[cc], v);
            }
            kk[r] = k * L2E;
            vv[r] = v;
            vsum[r] += v;
        }
        if (mloc[j]) {
            uint4 kw;
            kw.x = pkh(kk[0], kk[1]);
            kw.y = pkh(kk[2], kk[3]);
            kw.z = pkh(kk[4], kk[5]);
            kw.w = pkh(0.0f, 0.0f);  // bias 0: all compacted cols unmasked
            *reinterpret_cast<uint4*>(&Ksm[slot * 8]) = kw;
#pragma unroll
            for (int r = 0; r < DIM; ++r)
                Vt[r * VROW + slot] = (unsigned short)bf16rn(vv[r]);
            Vt[6 * VROW + slot] = 0x3F80u;  // ones row (denominator)
            rowl[slot] = (unsigned short)t;
            ++slot;
        }
    }
    const int NT16 = (Nu + 15) & ~15;
    if (tid < NT16 - Nu) {  // pad tail tile: p==0 via bias, V zeroed
        const int s = Nu + tid;
        uint4 kw; kw.x = 0; kw.y = 0; kw.z = 0; kw.w = pkh(-1024.0f, 0.0f);
        *reinterpret_cast<uint4*>(&Ksm[s * 8]) = kw;
#pragma unroll
        for (int r = 0; r < 7; ++r) Vt[r * VROW + s] = 0;
        rowl[s] = 0;
    }

    // ---- Phase 3 (block 0 only): meanV + masked-row outputs ----
    if (blk == 0) {
#pragma unroll
        for (int r = 0; r < DIM; ++r) {
#pragma unroll
            for (int off = 1; off < 64; off <<= 1)
                vsum[r] += __shfl_xor(vsum[r], off);
        }
        if (lane == 0) {
#pragma unroll
            for (int r = 0; r < DIM; ++r) wred[wid * 8 + r] = vsum[r];
        }
    }
    __syncthreads();
    if (blk == 0) {
        float meanV[DIM];
#pragma unroll
        for (int r = 0; r < DIM; ++r) {
            float s = 0.0f;
#pragma unroll
            for (int w = 0; w < NW; ++w) s += wred[w * 8 + r];
            meanV[r] = s * (1.0f / SEQ);
        }
#pragma unroll
        for (int j = 0; j < 4; ++j) {
            if (!mloc[j]) {
                float* o = out + ((size_t)b * SEQ + t0 + j) * DIM;
                o[0] = meanV[0]; o[1] = meanV[1]; o[2] = meanV[2];
                o[3] = meanV[3]; o[4] = meanV[4]; o[5] = meanV[5];
            }
        }
    }

    // ---- Phase 4: MFMA loop over compacted tiles for this block's rows ----
    const int s0 = rowbase + wid * 16;
    if (s0 >= Nu) return;  // partial block tail; no barriers below
    const int r15 = lane & 15, g = lane >> 4;
    const int sidx = s0 + r15;
    const int srow = rowl[sidx < Nu ? sidx : Nu - 1];

    float qq[DIM];
    {
        const float2* xp = reinterpret_cast<const float2*>(Xb + srow * DIM);
        float2 x01 = xp[0], x23 = xp[1], x45 = xp[2];
        float x[DIM] = {x01.x, x01.y, x23.x, x23.y, x45.x, x45.y};
#pragma unroll
        for (int r = 0; r < DIM; ++r) {
            float q = bq[r];
#pragma unroll
            for (int cc = 0; cc < DIM; ++cc) q = fmaf(Wq[r * DIM + cc], x[cc], q);
            qq[r] = q;  // compacted rows are all unmasked
        }
    }
    FragU qf;
    qf.u.x = (g == 0) ? pkh(qq[0], qq[1]) : (g == 1) ? pkh(qq[4], qq[5]) : 0u;
    qf.u.y = (g == 0) ? pkh(qq[2], qq[3]) : (g == 1) ? pkh(1.0f, 0.0f) : 0u;

    const f32x4 zero4 = {0.0f, 0.0f, 0.0f, 0.0f};
    f32x4 acc = zero4;
    {
        const int dcl = (r15 < 6) ? r15 : 6;
        int kidx = r15 * 8 + (g & 1) * 4;
        int vidx = dcl * VROW + g * 4;
        const int ntiles = NT16 >> 4;
#pragma unroll 4
        for (int tt = 0; tt < ntiles; ++tt) {
            half4F kf = *reinterpret_cast<const half4F*>(&Ksm[kidx]);
            bf16x4 vf = *reinterpret_cast<const bf16x4*>(&Vt[vidx]);
            f32x4 d = __builtin_amdgcn_mfma_f32_16x16x16f16(kf, qf.h, zero4, 0, 0, 0);
            FragU pa;
            pa.u.x = pkbf_trunc(__builtin_amdgcn_exp2f(d[0]),
                                __builtin_amdgcn_exp2f(d[1]));
            pa.u.y = pkbf_trunc(__builtin_amdgcn_exp2f(d[2]),
                                __builtin_amdgcn_exp2f(d[3]));
            acc = mfma_bf16_(pa.b, vf, acc);
            kidx += 128;
            vidx += 16;
        }
    }

    // ---- Epilogue: numerators / denominator, scatter to original rows ----
    const int srcl = (lane & 48) | 6;
#pragma unroll
    for (int r = 0; r < 4; ++r) {
        const float dnm = __shfl(acc[r], srcl);
        const float val = acc[r] * __builtin_amdgcn_rcpf(dnm);
        const int oidx = s0 + g * 4 + r;
        if (r15 < 6 && oidx < Nu) {
            out[((size_t)b * SEQ + rowl[oidx]) * DIM + r15] = val;
        }
    }
}

extern "C" void kernel_launch(void* const* d_in, const int* in_sizes, int n_in,
                              void* d_out, int out_size, void* d_ws, size_t ws_size,
                              hipStream_t stream) {
    const float* X  = (const float*)d_in[0];
    const int* mask = (const int*)d_in[1];
    const float* Wq = (const float*)d_in[2];
    const float* bq = (const float*)d_in[3];
    const float* Wk = (const float*)d_in[4];
    const float* bk = (const float*)d_in[5];
    const float* Wv = (const float*)d_in[6];
    const float* bv = (const float*)d_in[7];
    float* out = (float*)d_out;

    const int B = in_sizes[0] / (SEQ * DIM);

    const size_t shmem = 32768 + 7 * VROW * 2 + 4096 + 256;  // 65904 B
    hipFuncSetAttribute(reinterpret_cast<const void*>(attn_fused),
                        hipFuncAttributeMaxDynamicSharedMemorySize, (int)shmem);

    dim3 grid(B * 16);
    attn_fused<<<grid, BLOCK, shmem, stream>>>(X, mask, Wq, bq, Wk, bk, Wv, bv, out);
}

// Round 19
// 24.006 us; speedup vs baseline: 1.5782x; 1.0313x over previous
//
#include <hip/hip_runtime.h>

#define SEQ 2048
#define DIM 6
#define NSEG 8               // prep segments per batch
#define SEGR (SEQ / NSEG)    // 256 rows per prep block
#define VROW 2056            // padded LDS V^T row stride

typedef _Float16 half4F __attribute__((ext_vector_type(4)));
typedef short bf16x4 __attribute__((ext_vector_type(4)));
typedef float f32x4 __attribute__((ext_vector_type(4)));

union FragU { uint2 u; half4F h; bf16x4 b; };

__device__ __forceinline__ unsigned pkh(float a, float b) {
    return __builtin_bit_cast(unsigned, __builtin_amdgcn_cvt_pkrtz(a, b));
}
__device__ __forceinline__ unsigned bf16rn(float x) {  // RNE (finite inputs)
    unsigned u = __builtin_bit_cast(unsigned, x);
    return (u + 0x7FFFu + ((u >> 16) & 1u)) >> 16;
}
__device__ __forceinline__ unsigned pkbf(float a, float b) {
    return bf16rn(a) | (bf16rn(b) << 16);
}
// Packed truncating f32->bf16 pair (P only): ONE v_perm_b32.
__device__ __forceinline__ unsigned pkbf_trunc(float a, float b) {
    return __builtin_amdgcn_perm(__builtin_bit_cast(unsigned, b),
                                 __builtin_bit_cast(unsigned, a),
                                 0x07060302u);
}

__device__ __forceinline__ f32x4 mfma_bf16_(bf16x4 a, bf16x4 b, f32x4 c) {
#if __has_builtin(__builtin_amdgcn_mfma_f32_16x16x16bf16_1k)
    return __builtin_amdgcn_mfma_f32_16x16x16bf16_1k(a, b, c, 0, 0, 0);
#else
    f32x4 d;
    asm("v_mfma_f32_16x16x16_bf16 %0, %1, %2, %3"
        : "=v"(d) : "v"(a), "v"(b), "v"(c));
    return d;
#endif
}

// ws layout:
//   Kc    [B][SEQ][8] fp16 : compacted K' = {k*log2e x6, 0, 0}
//   Vc    [B][SEQ][8] bf16 : compacted V' row-major (transposed in attn LDS)
//   rowl  [B][SEQ] u16     : compacted index -> original row
//   vsumP [B][NSEG][8] f32 : per-segment V sums (for meanV)
//   nuArr [B] int          : unmasked count
// Masked cols excluded (exact: ref softmax weight underflows to 0).
// Masked rows = mean(V over ALL t), f32-exact.

__launch_bounds__(256)
__global__ void prep(const float* __restrict__ X, const int* __restrict__ mask,
                     const float* __restrict__ Wk, const float* __restrict__ bk,
                     const float* __restrict__ Wv, const float* __restrict__ bv,
                     __fp16* __restrict__ Kc, unsigned short* __restrict__ Vc,
                     unsigned short* __restrict__ rowl,
                     float* __restrict__ vsumP, int* __restrict__ nuArr) {
    __shared__ unsigned char msk[SEQ];
    __shared__ int sA[256], sB[256];
    __shared__ float vred[4][8];
    const int b = blockIdx.x >> 3, seg = blockIdx.x & 7;
    const int tid = threadIdx.x;
    const int* mb = mask + (size_t)b * SEQ;
    const float L2E = 1.44269504088896f;

    // full-batch mask -> LDS; per-thread count over its 8 entries
    int cnt = 0;
#pragma unroll
    for (int j = 0; j < 8; ++j) {
        const int m = (mb[tid * 8 + j] != 0);
        msk[tid * 8 + j] = (unsigned char)m;
        cnt += m;
    }
    sA[tid] = cnt;
    __syncthreads();
    int* src = sA; int* dst = sB;
    for (int off = 1; off < 256; off <<= 1) {
        int v = src[tid];
        if (tid >= off) v += src[tid - off];
        dst[tid] = v;
        __syncthreads();
        int* tmp = src; src = dst; dst = tmp;
    }
    if (seg == 0 && tid == 0) nuArr[b] = src[255];

    // this thread's row and compacted slot
    const int t = seg * SEGR + tid;
    const int i8 = t >> 3;
    int slot = (i8 > 0) ? src[i8 - 1] : 0;
    for (int j = i8 * 8; j < t; ++j) slot += msk[j];

    // project row t once
    const float2* xp = reinterpret_cast<const float2*>(X + ((size_t)b * SEQ + t) * DIM);
    float2 x01 = xp[0], x23 = xp[1], x45 = xp[2];
    float x[DIM] = {x01.x, x01.y, x23.x, x23.y, x45.x, x45.y};
    float kk[DIM], vv[DIM];
#pragma unroll
    for (int r = 0; r < DIM; ++r) {
        float k = bk[r], v = bv[r];
#pragma unroll
        for (int c = 0; c < DIM; ++c) {
            k = fmaf(Wk[r * DIM + c], x[c], k);
            v = fmaf(Wv[r * DIM + c], x[c], v);
        }
        kk[r] = k * L2E;
        vv[r] = v;
    }
    if (msk[t]) {
        uint4 kw;
        kw.x = pkh(kk[0], kk[1]);
        kw.y = pkh(kk[2], kk[3]);
        kw.z = pkh(kk[4], kk[5]);
        kw.w = 0u;  // bias 0: compacted cols are all unmasked
        *reinterpret_cast<uint4*>(Kc + ((size_t)b * SEQ + slot) * 8) = kw;
        uint4 vw;
        vw.x = pkbf(vv[0], vv[1]);
        vw.y = pkbf(vv[2], vv[3]);
        vw.z = pkbf(vv[4], vv[5]);
        vw.w = 0u;
        *reinterpret_cast<uint4*>(Vc + ((size_t)b * SEQ + slot) * 8) = vw;
        rowl[(size_t)b * SEQ + slot] = (unsigned short)t;
    }

    // per-segment V sum (ALL rows) -> vsumP, deterministic tree
    const int lane = tid & 63, wid = tid >> 6;
#pragma unroll
    for (int r = 0; r < DIM; ++r) {
        float s = vv[r];
#pragma unroll
        for (int off = 1; off < 64; off <<= 1) s += __shfl_xor(s, off);
        if (lane == 0) vred[wid][r] = s;
    }
    __syncthreads();
    if (tid < DIM) {
        vsumP[((size_t)b * NSEG + seg) * 8 + tid] =
            vred[0][tid] + vred[1][tid] + vred[2][tid] + vred[3][tid];
    }
}

__launch_bounds__(512, 2)
__global__ void attn_mfma(const float* __restrict__ X,
                          const int* __restrict__ mask,
                          const float* __restrict__ Wq, const float* __restrict__ bq,
                          const __fp16* __restrict__ Kc,
                          const unsigned short* __restrict__ Vc,
                          const unsigned short* __restrict__ rowl,
                          const float* __restrict__ vsumP,
                          const int* __restrict__ nuArr,
                          float* __restrict__ out) {
    __shared__ __align__(16) __fp16 Ksm[SEQ * 8];          // 32 KB
    __shared__ __align__(16) unsigned short Vt[7 * VROW];  // 28.8 KB

    const int b = blockIdx.x >> 4, blk = blockIdx.x & 15;
    const int tid = threadIdx.x;
    const int Nu = nuArr[b];

    // masked-row fill for original rows [blk*128, +128): meanV (f32-exact)
    if (tid < 128) {
        const int t = blk * 128 + tid;
        if (mask[(size_t)b * SEQ + t] == 0) {
            float* o = out + ((size_t)b * SEQ + t) * DIM;
#pragma unroll
            for (int r = 0; r < DIM; ++r) {
                float s = 0.0f;
#pragma unroll
                for (int g2 = 0; g2 < NSEG; ++g2)
                    s += vsumP[((size_t)b * NSEG + g2) * 8 + r];
                o[r] = s * (1.0f / SEQ);
            }
        }
    }

    const int rowbase = blk * 128;
    if (rowbase >= Nu) return;  // fill-only block
    const int NT16 = (Nu + 15) & ~15;

    // bulk-stage compacted K' / V' from L2; V transposed into LDS
    const uint4* kg = reinterpret_cast<const uint4*>(Kc + (size_t)b * SEQ * 8);
    const uint4* vg = reinterpret_cast<const uint4*>(Vc + (size_t)b * SEQ * 8);
    for (int i = tid; i < NT16; i += 512) {
        uint4 kw, vw;
        if (i < Nu) { kw = kg[i]; vw = vg[i]; }
        else { kw = make_uint4(0, 0, 0, pkh(-1024.0f, 0.0f)); vw = make_uint4(0, 0, 0, 0); }
        reinterpret_cast<uint4*>(Ksm)[i] = kw;
        Vt[0 * VROW + i] = (unsigned short)(vw.x & 0xFFFFu);
        Vt[1 * VROW + i] = (unsigned short)(vw.x >> 16);
        Vt[2 * VROW + i] = (unsigned short)(vw.y & 0xFFFFu);
        Vt[3 * VROW + i] = (unsigned short)(vw.y >> 16);
        Vt[4 * VROW + i] = (unsigned short)(vw.z & 0xFFFFu);
        Vt[5 * VROW + i] = (unsigned short)(vw.z >> 16);
        Vt[6 * VROW + i] = (i < Nu) ? 0x3F80u : 0u;  // ones row (denominator)
    }
    __syncthreads();

    const int lane = tid & 63, wid = tid >> 6;
    const int s0 = rowbase + wid * 16;
    if (s0 >= Nu) return;  // tail waves; no barriers below
    const int r15 = lane & 15, g = lane >> 4;
    const int sidx = s0 + r15;
    const int srow = rowl[(size_t)b * SEQ + (sidx < Nu ? sidx : Nu - 1)];

    // Q' projection for compacted row srow (4 lane-copies per row)
    float qq[DIM];
    {
        const float2* xp =
            reinterpret_cast<const float2*>(X + ((size_t)b * SEQ + srow) * DIM);
        float2 x01 = xp[0], x23 = xp[1], x45 = xp[2];
        float x[DIM] = {x01.x, x01.y, x23.x, x23.y, x45.x, x45.y};
#pragma unroll
        for (int r = 0; r < DIM; ++r) {
            float q = bq[r];
#pragma unroll
            for (int c = 0; c < DIM; ++c) q = fmaf(Wq[r * DIM + c], x[c], q);
            qq[r] = q;  // compacted rows are all unmasked
        }
    }
    FragU qf;
    qf.u.x = (g == 0) ? pkh(qq[0], qq[1]) : (g == 1) ? pkh(qq[4], qq[5]) : 0u;
    qf.u.y = (g == 0) ? pkh(qq[2], qq[3]) : (g == 1) ? pkh(1.0f, 0.0f) : 0u;

    const f32x4 zero4 = {0.0f, 0.0f, 0.0f, 0.0f};
    f32x4 acc = zero4;
    {
        const int dcl = (r15 < 6) ? r15 : 6;
        int kidx = r15 * 8 + (g & 1) * 4;
        int vidx = dcl * VROW + g * 4;
        const int ntiles = NT16 >> 4;
#pragma unroll 4
        for (int tt = 0; tt < ntiles; ++tt) {
            half4F kf = *reinterpret_cast<const half4F*>(&Ksm[kidx]);
            bf16x4 vf = *reinterpret_cast<const bf16x4*>(&Vt[vidx]);
            f32x4 d = __builtin_amdgcn_mfma_f32_16x16x16f16(kf, qf.h, zero4, 0, 0, 0);
            FragU pa;
            pa.u.x = pkbf_trunc(__builtin_amdgcn_exp2f(d[0]),
                                __builtin_amdgcn_exp2f(d[1]));
            pa.u.y = pkbf_trunc(__builtin_amdgcn_exp2f(d[2]),
                                __builtin_amdgcn_exp2f(d[3]));
            acc = mfma_bf16_(pa.b, vf, acc);
            kidx += 128;
            vidx += 16;
        }
    }

    // epilogue: numerators / denominator; scatter to original rows
    const int srcl = (lane & 48) | 6;
#pragma unroll
    for (int r = 0; r < 4; ++r) {
        const float dnm = __shfl(acc[r], srcl);
        const float val = acc[r] * __builtin_amdgcn_rcpf(dnm);
        const int oidx = s0 + g * 4 + r;
        if (r15 < 6 && oidx < Nu) {
            const int orow = rowl[(size_t)b * SEQ + oidx];
            out[((size_t)b * SEQ + orow) * DIM + r15] = val;
        }
    }
}

extern "C" void kernel_launch(void* const* d_in, const int* in_sizes, int n_in,
                              void* d_out, int out_size, void* d_ws, size_t ws_size,
                              hipStream_t stream) {
    const float* X  = (const float*)d_in[0];
    const int* mask = (const int*)d_in[1];
    const float* Wq = (const float*)d_in[2];
    const float* bq = (const float*)d_in[3];
    const float* Wk = (const float*)d_in[4];
    const float* bk = (const float*)d_in[5];
    const float* Wv = (const float*)d_in[6];
    const float* bv = (const float*)d_in[7];
    float* out = (float*)d_out;

    const int B = in_sizes[0] / (SEQ * DIM);

    __fp16* Kc = (__fp16*)d_ws;                                          // B*SEQ*8
    unsigned short* Vc = (unsigned short*)(Kc + (size_t)B * SEQ * 8);    // B*SEQ*8
    unsigned short* rowl = Vc + (size_t)B * SEQ * 8;                     // B*SEQ
    float* vsumP = (float*)(rowl + (size_t)B * SEQ);                     // B*NSEG*8
    int* nuArr = (int*)(vsumP + (size_t)B * NSEG * 8);                   // B

    prep<<<dim3(B * NSEG), 256, 0, stream>>>(X, mask, Wk, bk, Wv, bv,
                                             Kc, Vc, rowl, vsumP, nuArr);
    attn_mfma<<<dim3(B * 16), 512, 0, stream>>>(X, mask, Wq, bq, Kc, Vc, rowl,
                                                vsumP, nuArr, out);
}

// Round 21
// 23.850 us; speedup vs baseline: 1.5885x; 1.0065x over previous
//
#include <hip/hip_runtime.h>

#define SEQ 2048
#define DIM 6
#define NSEG 8               // prep segments per batch
#define SEGR (SEQ / NSEG)    // 256 rows per prep block
#define VROW 2056            // padded LDS V^T row stride

typedef _Float16 half4F __attribute__((ext_vector_type(4)));
typedef short bf16x4 __attribute__((ext_vector_type(4)));
typedef float f32x4 __attribute__((ext_vector_type(4)));

union FragU { uint2 u; half4F h; bf16x4 b; };

__device__ __forceinline__ unsigned pkh(float a, float b) {
    return __builtin_bit_cast(unsigned, __builtin_amdgcn_cvt_pkrtz(a, b));
}
__device__ __forceinline__ unsigned bf16rn(float x) {  // RNE (finite inputs)
    unsigned u = __builtin_bit_cast(unsigned, x);
    return (u + 0x7FFFu + ((u >> 16) & 1u)) >> 16;
}
__device__ __forceinline__ unsigned pkbf(float a, float b) {
    return bf16rn(a) | (bf16rn(b) << 16);
}
// Packed truncating f32->bf16 pair (P only): ONE v_perm_b32.
__device__ __forceinline__ unsigned pkbf_trunc(float a, float b) {
    return __builtin_amdgcn_perm(__builtin_bit_cast(unsigned, b),
                                 __builtin_bit_cast(unsigned, a),
                                 0x07060302u);
}

__device__ __forceinline__ f32x4 mfma_bf16_(bf16x4 a, bf16x4 b, f32x4 c) {
#if __has_builtin(__builtin_amdgcn_mfma_f32_16x16x16bf16_1k)
    return __builtin_amdgcn_mfma_f32_16x16x16bf16_1k(a, b, c, 0, 0, 0);
#else
    f32x4 d;
    asm("v_mfma_f32_16x16x16_bf16 %0, %1, %2, %3"
        : "=v"(d) : "v"(a), "v"(b), "v"(c));
    return d;
#endif
}

// ws: Kc [B][SEQ][8] fp16 | Vc [B][SEQ][8] bf16 | rowl [B][SEQ] u16 |
//     vsumP [B][NSEG][8] f32 | nuArr [B] int
// Masked cols excluded (exact: ref weight underflows to 0).
// Masked rows = mean(V over ALL t) (f32-exact).

__launch_bounds__(256)
__global__ void prep(const float* __restrict__ X, const int* __restrict__ mask,
                     const float* __restrict__ Wk, const float* __restrict__ bk,
                     const float* __restrict__ Wv, const float* __restrict__ bv,
                     __fp16* __restrict__ Kc, unsigned short* __restrict__ Vc,
                     unsigned short* __restrict__ rowl,
                     float* __restrict__ vsumP, int* __restrict__ nuArr) {
    __shared__ unsigned char msk[SEQ];
    __shared__ int wexcl[256];   // per-thread exclusive prefix within its wave
    __shared__ int wtot[4];      // per-wave totals
    __shared__ float vred[4][8];
    const int b = blockIdx.x >> 3, seg = blockIdx.x & 7;
    const int tid = threadIdx.x;
    const int lane = tid & 63, wid = tid >> 6;
    const int* mb = mask + (size_t)b * SEQ;
    const float L2E = 1.44269504088896f;

    // mask -> LDS; per-thread count over its 8 entries; wave-level shfl scan
    int cnt = 0;
#pragma unroll
    for (int j = 0; j < 8; ++j) {
        const int m = (mb[tid * 8 + j] != 0);
        msk[tid * 8 + j] = (unsigned char)m;
        cnt += m;
    }
    int inc = cnt;
#pragma unroll
    for (int off = 1; off < 64; off <<= 1) {
        const int t2 = __shfl_up(inc, off);
        if (lane >= off) inc += t2;
    }
    wexcl[tid] = inc - cnt;
    if (lane == 63) wtot[wid] = inc;
    __syncthreads();
    const int Nu = wtot[0] + wtot[1] + wtot[2] + wtot[3];
    if (seg == 0 && tid == 0) nuArr[b] = Nu;

    // this thread's row and compacted slot
    const int t = seg * SEGR + tid;
    const int i8 = t >> 3;
    int slot = wexcl[i8];
    {
        const int w = i8 >> 6;
        if (w > 0) slot += wtot[0];
        if (w > 1) slot += wtot[1];
        if (w > 2) slot += wtot[2];
    }
    for (int j = i8 * 8; j < t; ++j) slot += msk[j];

    // project row t once
    const float2* xp = reinterpret_cast<const float2*>(X + ((size_t)b * SEQ + t) * DIM);
    float2 x01 = xp[0], x23 = xp[1], x45 = xp[2];
    float x[DIM] = {x01.x, x01.y, x23.x, x23.y, x45.x, x45.y};
    float kk[DIM], vv[DIM];
#pragma unroll
    for (int r = 0; r < DIM; ++r) {
        float k = bk[r], v = bv[r];
#pragma unroll
        for (int c = 0; c < DIM; ++c) {
            k = fmaf(Wk[r * DIM + c], x[c], k);
            v = fmaf(Wv[r * DIM + c], x[c], v);
        }
        kk[r] = k * L2E;
        vv[r] = v;
    }
    if (msk[t]) {
        uint4 kw;
        kw.x = pkh(kk[0], kk[1]);
        kw.y = pkh(kk[2], kk[3]);
        kw.z = pkh(kk[4], kk[5]);
        kw.w = 0u;  // bias 0: compacted cols are all unmasked
        *reinterpret_cast<uint4*>(Kc + ((size_t)b * SEQ + slot) * 8) = kw;
        uint4 vw;
        vw.x = pkbf(vv[0], vv[1]);
        vw.y = pkbf(vv[2], vv[3]);
        vw.z = pkbf(vv[4], vv[5]);
        vw.w = 0u;
        *reinterpret_cast<uint4*>(Vc + ((size_t)b * SEQ + slot) * 8) = vw;
        rowl[(size_t)b * SEQ + slot] = (unsigned short)t;
    }

    // per-segment V sum (ALL rows), deterministic
#pragma unroll
    for (int r = 0; r < DIM; ++r) {
        float s = vv[r];
#pragma unroll
        for (int off = 1; off < 64; off <<= 1) s += __shfl_xor(s, off);
        if (lane == 0) vred[wid][r] = s;
    }
    __syncthreads();
    if (tid < DIM) {
        vsumP[((size_t)b * NSEG + seg) * 8 + tid] =
            vred[0][tid] + vred[1][tid] + vred[2][tid] + vred[3][tid];
    }
}

// attn: 16 blocks/batch x 8 waves. Wave PAIR p owns s-tile rt = pass*64+blk*4+p;
// halves split t-tiles (even/odd); partials combine by addition via LDS.
__launch_bounds__(512, 2)
__global__ void attn_mfma(const float* __restrict__ X,
                          const int* __restrict__ mask,
                          const float* __restrict__ Wq, const float* __restrict__ bq,
                          const __fp16* __restrict__ Kc,
                          const unsigned short* __restrict__ Vc,
                          const unsigned short* __restrict__ rowl,
                          const float* __restrict__ vsumP,
                          const int* __restrict__ nuArr,
                          float* __restrict__ out) {
    extern __shared__ __align__(16) char smem[];
    __fp16* Ksm = (__fp16*)smem;                               // [2048][8] 32K
    unsigned short* Vt = (unsigned short*)(smem + 32768);      // [7][VROW] 28.8K
    f32x4* comb = (f32x4*)(smem + 32768 + 7 * VROW * 2);       // [4][64] 4K

    const int b = blockIdx.x >> 4, blk = blockIdx.x & 15;
    const int tid = threadIdx.x;
    const int Nu = nuArr[b];
    const int NT16 = (Nu + 15) & ~15;
    const int ntiles = NT16 >> 4;
    const int nstile = (Nu + 15) >> 4;
    const int npass = (nstile + 63) >> 6;

    // masked-row fill for original rows [blk*128, +128): meanV (f32-exact)
    if (tid < 128) {
        const int t = blk * 128 + tid;
        if (mask[(size_t)b * SEQ + t] == 0) {
            float* o = out + ((size_t)b * SEQ + t) * DIM;
#pragma unroll
            for (int r = 0; r < DIM; ++r) {
                float s = 0.0f;
#pragma unroll
                for (int g2 = 0; g2 < NSEG; ++g2)
                    s += vsumP[((size_t)b * NSEG + g2) * 8 + r];
                o[r] = s * (1.0f / SEQ);
            }
        }
    }

    // bulk-stage compacted K'/V' from L2; V transposed into LDS rows
    const uint4* kg = reinterpret_cast<const uint4*>(Kc + (size_t)b * SEQ * 8);
    const uint4* vg = reinterpret_cast<const uint4*>(Vc + (size_t)b * SEQ * 8);
    for (int i = tid; i < NT16; i += 512) {
        uint4 kw, vw;
        if (i < Nu) { kw = kg[i]; vw = vg[i]; }
        else { kw = make_uint4(0, 0, 0, pkh(-1024.0f, 0.0f)); vw = make_uint4(0, 0, 0, 0); }
        reinterpret_cast<uint4*>(Ksm)[i] = kw;
        Vt[0 * VROW + i] = (unsigned short)(vw.x & 0xFFFFu);
        Vt[1 * VROW + i] = (unsigned short)(vw.x >> 16);
        Vt[2 * VROW + i] = (unsigned short)(vw.y & 0xFFFFu);
        Vt[3 * VROW + i] = (unsigned short)(vw.y >> 16);
        Vt[4 * VROW + i] = (unsigned short)(vw.z & 0xFFFFu);
        Vt[5 * VROW + i] = (unsigned short)(vw.z >> 16);
        Vt[6 * VROW + i] = (i < Nu) ? 0x3F80u : 0u;  // ones row (denominator)
    }
    __syncthreads();

    const int lane = tid & 63, wid = tid >> 6;
    const int pair = wid >> 1, half = wid & 1;
    const int r15 = lane & 15, g = lane >> 4;
    const int dcl = (r15 < 6) ? r15 : 6;
    const f32x4 zero4 = {0.0f, 0.0f, 0.0f, 0.0f};

    for (int pass = 0; pass < npass; ++pass) {
        const int rt = pass * 64 + blk * 4 + pair;
        const bool active = (rt < nstile);
        f32x4 acc = zero4;
        if (active) {
            const int s0 = rt * 16;
            const int sidx = s0 + r15;
            const int srow = rowl[(size_t)b * SEQ + (sidx < Nu ? sidx : Nu - 1)];
            // Q' projection (both halves compute the same fragment)
            float qq[DIM];
            {
                const float2* xp = reinterpret_cast<const float2*>(
                    X + ((size_t)b * SEQ + srow) * DIM);
                float2 x01 = xp[0], x23 = xp[1], x45 = xp[2];
                float x[DIM] = {x01.x, x01.y, x23.x, x23.y, x45.x, x45.y};
#pragma unroll
                for (int r = 0; r < DIM; ++r) {
                    float q = bq[r];
#pragma unroll
                    for (int c = 0; c < DIM; ++c)
                        q = fmaf(Wq[r * DIM + c], x[c], q);
                    qq[r] = q;
                }
            }
            FragU qf;
            qf.u.x = (g == 0) ? pkh(qq[0], qq[1]) : (g == 1) ? pkh(qq[4], qq[5]) : 0u;
            qf.u.y = (g == 0) ? pkh(qq[2], qq[3]) : (g == 1) ? pkh(1.0f, 0.0f) : 0u;

            int kidx = half * 128 + r15 * 8 + (g & 1) * 4;
            int vidx = dcl * VROW + half * 16 + g * 4;
#pragma unroll 2
            for (int tt = half; tt < ntiles; tt += 2) {
                half4F kf = *reinterpret_cast<const half4F*>(&Ksm[kidx]);
                bf16x4 vf = *reinterpret_cast<const bf16x4*>(&Vt[vidx]);
                f32x4 d = __builtin_amdgcn_mfma_f32_16x16x16f16(kf, qf.h, zero4, 0, 0, 0);
                FragU pa;
                pa.u.x = pkbf_trunc(__builtin_amdgcn_exp2f(d[0]),
                                    __builtin_amdgcn_exp2f(d[1]));
                pa.u.y = pkbf_trunc(__builtin_amdgcn_exp2f(d[2]),
                                    __builtin_amdgcn_exp2f(d[3]));
                acc = mfma_bf16_(pa.b, vf, acc);
                kidx += 256;
                vidx += 32;
            }
        }
        if (half == 1 && active) comb[pair * 64 + lane] = acc;
        __syncthreads();
        if (half == 0 && active) {
            const f32x4 oth = comb[pair * 64 + lane];
            acc = acc + oth;
            const int s0 = rt * 16;
            const int srcl = (lane & 48) | 6;
#pragma unroll
            for (int r = 0; r < 4; ++r) {
                const float dnm = __shfl(acc[r], srcl);
                const float val = acc[r] * __builtin_amdgcn_rcpf(dnm);
                const int oidx = s0 + g * 4 + r;
                if (r15 < 6 && oidx < Nu) {
                    const int orow = rowl[(size_t)b * SEQ + oidx];
                    out[((size_t)b * SEQ + orow) * DIM + r15] = val;
                }
            }
        }
        __syncthreads();  // protect comb before next pass overwrites
    }
}

extern "C" void kernel_launch(void* const* d_in, const int* in_sizes, int n_in,
                              void* d_out, int out_size, void* d_ws, size_t ws_size,
                              hipStream_t stream) {
    const float* X  = (const float*)d_in[0];
    const int* mask = (const int*)d_in[1];
    const float* Wq = (const float*)d_in[2];
    const float* bq = (const float*)d_in[3];
    const float* Wk = (const float*)d_in[4];
    const float* bk = (const float*)d_in[5];
    const float* Wv = (const float*)d_in[6];
    const float* bv = (const float*)d_in[7];
    float* out = (float*)d_out;

    const int B = in_sizes[0] / (SEQ * DIM);

    __fp16* Kc = (__fp16*)d_ws;                                          // B*SEQ*8
    unsigned short* Vc = (unsigned short*)(Kc + (size_t)B * SEQ * 8);    // B*SEQ*8
    unsigned short* rowl = Vc + (size_t)B * SEQ * 8;                     // B*SEQ
    float* vsumP = (float*)(rowl + (size_t)B * SEQ);                     // B*NSEG*8
    int* nuArr = (int*)(vsumP + (size_t)B * NSEG * 8);                   // B

    const size_t shmem = 32768 + (size_t)7 * VROW * 2 + 4096;  // 65648 B
    hipFuncSetAttribute(reinterpret_cast<const void*>(attn_mfma),
                        hipFuncAttributeMaxDynamicSharedMemorySize, (int)shmem);

    prep<<<dim3(B * NSEG), 256, 0, stream>>>(X, mask, Wk, bk, Wv, bv,
                                             Kc, Vc, rowl, vsumP, nuArr);
    attn_mfma<<<dim3(B * 16), 512, shmem, stream>>>(X, mask, Wq, bq, Kc, Vc, rowl,
                                                    vsumP, nuArr, out);
}

// Round 25
// 22.768 us; speedup vs baseline: 1.6640x; 1.0475x over previous
//
#include <hip/hip_runtime.h>

#define SEQ 2048
#define DIM 6
#define NSEG 8               // prep segments per batch
#define SEGR (SEQ / NSEG)    // 256 rows per prep block
#define VROW 2056            // padded LDS V^T row stride
#define CH 8                 // t-tiles per statically-unrolled chunk

typedef _Float16 half4F __attribute__((ext_vector_type(4)));
typedef short bf16x4 __attribute__((ext_vector_type(4)));
typedef float f32x4 __attribute__((ext_vector_type(4)));

union FragU { uint2 u; half4F h; bf16x4 b; };

__device__ __forceinline__ unsigned pkh(float a, float b) {
    return __builtin_bit_cast(unsigned, __builtin_amdgcn_cvt_pkrtz(a, b));
}
__device__ __forceinline__ unsigned bf16rn(float x) {  // RNE (finite inputs)
    unsigned u = __builtin_bit_cast(unsigned, x);
    return (u + 0x7FFFu + ((u >> 16) & 1u)) >> 16;
}
__device__ __forceinline__ unsigned pkbf(float a, float b) {
    return bf16rn(a) | (bf16rn(b) << 16);
}
// Packed truncating f32->bf16 pair (P only): ONE v_perm_b32.
__device__ __forceinline__ unsigned pkbf_trunc(float a, float b) {
    return __builtin_amdgcn_perm(__builtin_bit_cast(unsigned, b),
                                 __builtin_bit_cast(unsigned, a),
                                 0x07060302u);
}

__device__ __forceinline__ f32x4 mfma_bf16_(bf16x4 a, bf16x4 b, f32x4 c) {
#if __has_builtin(__builtin_amdgcn_mfma_f32_16x16x16bf16_1k)
    return __builtin_amdgcn_mfma_f32_16x16x16bf16_1k(a, b, c, 0, 0, 0);
#else
    f32x4 d;
    asm("v_mfma_f32_16x16x16_bf16 %0, %1, %2, %3"
        : "=v"(d) : "v"(a), "v"(b), "v"(c));
    return d;
#endif
}

// ws: Kc [B][SEQ][8] fp16 | Vc [B][SEQ][8] bf16 | rowl [B][SEQ] u16 |
//     vsumP [B][NSEG][8] f32 | nuArr [B] int
// Masked cols excluded (exact: ref weight underflows to 0).
// Masked rows = mean(V over ALL t) (f32-exact).

__launch_bounds__(256)
__global__ void prep(const float* __restrict__ X, const int* __restrict__ mask,
                     const float* __restrict__ Wk, const float* __restrict__ bk,
                     const float* __restrict__ Wv, const float* __restrict__ bv,
                     __fp16* __restrict__ Kc, unsigned short* __restrict__ Vc,
                     unsigned short* __restrict__ rowl,
                     float* __restrict__ vsumP, int* __restrict__ nuArr) {
    __shared__ unsigned char msk[SEQ];
    __shared__ int wexcl[256];
    __shared__ int wtot[4];
    __shared__ float vred[4][8];
    const int b = blockIdx.x >> 3, seg = blockIdx.x & 7;
    const int tid = threadIdx.x;
    const int lane = tid & 63, wid = tid >> 6;
    const int* mb = mask + (size_t)b * SEQ;
    const float L2E = 1.44269504088896f;

    int cnt = 0;
#pragma unroll
    for (int j = 0; j < 8; ++j) {
        const int m = (mb[tid * 8 + j] != 0);
        msk[tid * 8 + j] = (unsigned char)m;
        cnt += m;
    }
    int inc = cnt;
#pragma unroll
    for (int off = 1; off < 64; off <<= 1) {
        const int t2 = __shfl_up(inc, off);
        if (lane >= off) inc += t2;
    }
    wexcl[tid] = inc - cnt;
    if (lane == 63) wtot[wid] = inc;
    __syncthreads();
    const int Nu = wtot[0] + wtot[1] + wtot[2] + wtot[3];
    if (seg == 0 && tid == 0) nuArr[b] = Nu;

    const int t = seg * SEGR + tid;
    const int i8 = t >> 3;
    int slot = wexcl[i8];
    {
        const int w = i8 >> 6;
        if (w > 0) slot += wtot[0];
        if (w > 1) slot += wtot[1];
        if (w > 2) slot += wtot[2];
    }
    for (int j = i8 * 8; j < t; ++j) slot += msk[j];

    const float2* xp = reinterpret_cast<const float2*>(X + ((size_t)b * SEQ + t) * DIM);
    float2 x01 = xp[0], x23 = xp[1], x45 = xp[2];
    float x[DIM] = {x01.x, x01.y, x23.x, x23.y, x45.x, x45.y};
    float kk[DIM], vv[DIM];
#pragma unroll
    for (int r = 0; r < DIM; ++r) {
        float k = bk[r], v = bv[r];
#pragma unroll
        for (int c = 0; c < DIM; ++c) {
            k = fmaf(Wk[r * DIM + c], x[c], k);
            v = fmaf(Wv[r * DIM + c], x[c], v);
        }
        kk[r] = k * L2E;
        vv[r] = v;
    }
    if (msk[t]) {
        uint4 kw;
        kw.x = pkh(kk[0], kk[1]);
        kw.y = pkh(kk[2], kk[3]);
        kw.z = pkh(kk[4], kk[5]);
        kw.w = 0u;  // bias 0: compacted cols are all unmasked
        *reinterpret_cast<uint4*>(Kc + ((size_t)b * SEQ + slot) * 8) = kw;
        uint4 vw;
        vw.x = pkbf(vv[0], vv[1]);
        vw.y = pkbf(vv[2], vv[3]);
        vw.z = pkbf(vv[4], vv[5]);
        vw.w = 0u;
        *reinterpret_cast<uint4*>(Vc + ((size_t)b * SEQ + slot) * 8) = vw;
        rowl[(size_t)b * SEQ + slot] = (unsigned short)t;
    }

#pragma unroll
    for (int r = 0; r < DIM; ++r) {
        float s = vv[r];
#pragma unroll
        for (int off = 1; off < 64; off <<= 1) s += __shfl_xor(s, off);
        if (lane == 0) vred[wid][r] = s;
    }
    __syncthreads();
    if (tid < DIM) {
        vsumP[((size_t)b * NSEG + seg) * 8 + tid] =
            vred[0][tid] + vred[1][tid] + vred[2][tid] + vred[3][tid];
    }
}

__launch_bounds__(512, 2)
__global__ void attn_mfma(const float* __restrict__ X,
                          const int* __restrict__ mask,
                          const float* __restrict__ Wq, const float* __restrict__ bq,
                          const __fp16* __restrict__ Kc,
                          const unsigned short* __restrict__ Vc,
                          const unsigned short* __restrict__ rowl,
                          const float* __restrict__ vsumP,
                          const int* __restrict__ nuArr,
                          float* __restrict__ out) {
    __shared__ __align__(16) __fp16 Ksm[SEQ * 8];          // 32 KB
    __shared__ __align__(16) unsigned short Vt[7 * VROW];  // 28.8 KB

    const int b = blockIdx.x >> 4, blk = blockIdx.x & 15;
    const int tid = threadIdx.x;
    const int Nu = nuArr[b];
    // pad compacted columns to a multiple of CH*16 so the main loop has a
    // statically-unrolled body (pads: bias -1024 -> p == 0 exactly, V = 0)
    const int NTC = (Nu + CH * 16 - 1) & ~(CH * 16 - 1);

    // masked-row fill for original rows [blk*128, +128): meanV (f32-exact)
    if (tid < 128) {
        const int t = blk * 128 + tid;
        if (mask[(size_t)b * SEQ + t] == 0) {
            float* o = out + ((size_t)b * SEQ + t) * DIM;
#pragma unroll
            for (int r = 0; r < DIM; ++r) {
                float s = 0.0f;
#pragma unroll
                for (int g2 = 0; g2 < NSEG; ++g2)
                    s += vsumP[((size_t)b * NSEG + g2) * 8 + r];
                o[r] = s * (1.0f / SEQ);
            }
        }
    }

    const int rowbase = blk * 128;
    if (rowbase >= Nu) return;  // fill-only block

    // bulk-stage compacted K'/V' from L2; V transposed into LDS rows
    const uint4* kg = reinterpret_cast<const uint4*>(Kc + (size_t)b * SEQ * 8);
    const uint4* vg = reinterpret_cast<const uint4*>(Vc + (size_t)b * SEQ * 8);
    for (int i = tid; i < NTC; i += 512) {
        uint4 kw, vw;
        if (i < Nu) { kw = kg[i]; vw = vg[i]; }
        else { kw = make_uint4(0, 0, 0, pkh(-1024.0f, 0.0f)); vw = make_uint4(0, 0, 0, 0); }
        reinterpret_cast<uint4*>(Ksm)[i] = kw;
        Vt[0 * VROW + i] = (unsigned short)(vw.x & 0xFFFFu);
        Vt[1 * VROW + i] = (unsigned short)(vw.x >> 16);
        Vt[2 * VROW + i] = (unsigned short)(vw.y & 0xFFFFu);
        Vt[3 * VROW + i] = (unsigned short)(vw.y >> 16);
        Vt[4 * VROW + i] = (unsigned short)(vw.z & 0xFFFFu);
        Vt[5 * VROW + i] = (unsigned short)(vw.z >> 16);
        Vt[6 * VROW + i] = (i < Nu) ? 0x3F80u : 0u;  // ones row (denominator)
    }
    __syncthreads();

    const int lane = tid & 63, wid = tid >> 6;
    const int s0 = rowbase + wid * 16;
    if (s0 >= Nu) return;  // tail waves; no barriers below
    const int r15 = lane & 15, g = lane >> 4;
    const int sidx = s0 + r15;
    const int srow = rowl[(size_t)b * SEQ + (sidx < Nu ? sidx : Nu - 1)];

    // Q' projection for compacted row srow (4 lane-copies per row)
    float qq[DIM];
    {
        const float2* xp =
            reinterpret_cast<const float2*>(X + ((size_t)b * SEQ + srow) * DIM);
        float2 x01 = xp[0], x23 = xp[1], x45 = xp[2];
        float x[DIM] = {x01.x, x01.y, x23.x, x23.y, x45.x, x45.y};
#pragma unroll
        for (int r = 0; r < DIM; ++r) {
            float q = bq[r];
#pragma unroll
            for (int c = 0; c < DIM; ++c) q = fmaf(Wq[r * DIM + c], x[c], q);
            qq[r] = q;  // compacted rows are all unmasked
        }
    }
    FragU qf;
    qf.u.x = (g == 0) ? pkh(qq[0], qq[1]) : (g == 1) ? pkh(qq[4], qq[5]) : 0u;
    qf.u.y = (g == 0) ? pkh(qq[2], qq[3]) : (g == 1) ? pkh(1.0f, 0.0f) : 0u;

    const f32x4 zero4 = {0.0f, 0.0f, 0.0f, 0.0f};
    f32x4 acc = zero4;
    {
        const int dcl = (r15 < 6) ? r15 : 6;
        int kidx = r15 * 8 + (g & 1) * 4;
        int vidx = dcl * VROW + g * 4;
        const int nchunk = NTC >> (4 + 3);  // tiles/CH
        // Chunked loop: runtime chunk count, compile-time CH-wide body.
        // All CH K/V fragments land in named registers (static indexing),
        // giving the scheduler a wide window to overlap QK(i+1) with exp(i)/PV(i).
        for (int c = 0; c < nchunk; ++c) {
            half4F kf[CH];
            bf16x4 vf[CH];
#pragma unroll
            for (int u = 0; u < CH; ++u) {
                kf[u] = *reinterpret_cast<const half4F*>(&Ksm[kidx + u * 128]);
                vf[u] = *reinterpret_cast<const bf16x4*>(&Vt[vidx + u * 16]);
            }
#pragma unroll
            for (int u = 0; u < CH; ++u) {
                f32x4 d = __builtin_amdgcn_mfma_f32_16x16x16f16(kf[u], qf.h, zero4, 0, 0, 0);
                FragU pa;
                pa.u.x = pkbf_trunc(__builtin_amdgcn_exp2f(d[0]),
                                    __builtin_amdgcn_exp2f(d[1]));
                pa.u.y = pkbf_trunc(__builtin_amdgcn_exp2f(d[2]),
                                    __builtin_amdgcn_exp2f(d[3]));
                acc = mfma_bf16_(pa.b, vf[u], acc);
            }
            kidx += CH * 128;
            vidx += CH * 16;
        }
    }

    // epilogue: numerators / denominator; scatter to original rows
    const int srcl = (lane & 48) | 6;
#pragma unroll
    for (int r = 0; r < 4; ++r) {
        const float dnm = __shfl(acc[r], srcl);
        const float val = acc[r] * __builtin_amdgcn_rcpf(dnm);
        const int oidx = s0 + g * 4 + r;
        if (r15 < 6 && oidx < Nu) {
            const int orow = rowl[(size_t)b * SEQ + oidx];
            out[((size_t)b * SEQ + orow) * DIM + r15] = val;
        }
    }
}

extern "C" void kernel_launch(void* const* d_in, const int* in_sizes, int n_in,
                              void* d_out, int out_size, void* d_ws, size_t ws_size,
                              hipStream_t stream) {
    const float* X  = (const float*)d_in[0];
    const int* mask = (const int*)d_in[1];
    const float* Wq = (const float*)d_in[2];
    const float* bq = (const float*)d_in[3];
    const float* Wk = (const float*)d_in[4];
    const float* bk = (const float*)d_in[5];
    const float* Wv = (const float*)d_in[6];
    const float* bv = (const float*)d_in[7];
    float* out = (float*)d_out;

    const int B = in_sizes[0] / (SEQ * DIM);

    __fp16* Kc = (__fp16*)d_ws;                                          // B*SEQ*8
    unsigned short* Vc = (unsigned short*)(Kc + (size_t)B * SEQ * 8);    // B*SEQ*8
    unsigned short* rowl = Vc + (size_t)B * SEQ * 8;                     // B*SEQ
    float* vsumP = (float*)(rowl + (size_t)B * SEQ);                     // B*NSEG*8
    int* nuArr = (int*)(vsumP + (size_t)B * NSEG * 8);                   // B

    prep<<<dim3(B * NSEG), 256, 0, stream>>>(X, mask, Wk, bk, Wv, bv,
                                             Kc, Vc, rowl, vsumP, nuArr);
    attn_mfma<<<dim3(B * 16), 512, 0, stream>>>(X, mask, Wq, bq, Kc, Vc, rowl,
                                                vsumP, nuArr, out);
}